// Round 1
// baseline (121.380 us; speedup 1.0000x reference)
//
#include <hip/hip_runtime.h>

// Sinkhorn on 8192 independent 64x64 f32 matrices.
// x stays in the form diag(u) * K * diag(v); each iteration is two 64x64
// matvecs (K*v on a per-lane row copy, K^T*u on a per-lane column copy)
// with v_readlane broadcasts. One wave per matrix, zero LDS.

static constexpr int   kIters = 20;
static constexpr float kEps   = 1e-6f;

__device__ __forceinline__ float bcast(float x, int lane) {
    return __int_as_float(__builtin_amdgcn_readlane(__float_as_int(x), lane));
}

__global__ __launch_bounds__(256) void sinkhorn64(const float* __restrict__ in,
                                                  float* __restrict__ out) {
    const int wid  = threadIdx.x >> 6;   // wave within block
    const int lane = threadIdx.x & 63;
    const long m   = (long)blockIdx.x * 4 + wid;   // matrix index, 0..8191
    const float* __restrict__ A = in  + m * 4096;
    float* __restrict__ O       = out + m * 4096;

    // Column copy: cK[i] = A[i][lane]   (fully coalesced: 64 x 256B)
    float cK[64];
#pragma unroll
    for (int i = 0; i < 64; ++i) cK[i] = A[(i << 6) + lane];

    // Row copy: rK[k] = A[lane][k]      (strided; lines are hot in L1/L2
    // because the column-copy load just fetched this same 16 KiB)
    float rK[64];
#pragma unroll
    for (int k = 0; k < 16; ++k) {
        const float4 f = *reinterpret_cast<const float4*>(A + (lane << 6) + (k << 2));
        rK[4 * k + 0] = f.x; rK[4 * k + 1] = f.y;
        rK[4 * k + 2] = f.z; rK[4 * k + 3] = f.w;
    }

    // Row max (lane-local on the row copy), then exp both copies.
    float mx = rK[0];
#pragma unroll
    for (int k = 1; k < 64; ++k) mx = fmaxf(mx, rK[k]);
#pragma unroll
    for (int k = 0; k < 64; ++k) rK[k] = __expf(rK[k] - mx);
#pragma unroll
    for (int i = 0; i < 64; ++i) cK[i] = __expf(cK[i] - bcast(mx, i));

    float u = 1.0f, v = 1.0f;

#pragma unroll 1
    for (int it = 0; it < kIters; ++it) {
        // w_i = (K v)_i on the row copy; broadcast v_j from lane j.
        float w0 = 0.f, w1 = 0.f, w2 = 0.f, w3 = 0.f;
#pragma unroll
        for (int j = 0; j < 64; j += 4) {
            w0 = fmaf(bcast(v, j + 0), rK[j + 0], w0);
            w1 = fmaf(bcast(v, j + 1), rK[j + 1], w1);
            w2 = fmaf(bcast(v, j + 2), rK[j + 2], w2);
            w3 = fmaf(bcast(v, j + 3), rK[j + 3], w3);
        }
        const float w = (w0 + w1) + (w2 + w3);
        // u <- u / (u*w + eps)
        u = u * __builtin_amdgcn_rcpf(fmaf(u, w, kEps));

        // t_j = (K^T u)_j on the column copy; broadcast u_i from lane i.
        float t0 = 0.f, t1 = 0.f, t2 = 0.f, t3 = 0.f;
#pragma unroll
        for (int i = 0; i < 64; i += 4) {
            t0 = fmaf(bcast(u, i + 0), cK[i + 0], t0);
            t1 = fmaf(bcast(u, i + 1), cK[i + 1], t1);
            t2 = fmaf(bcast(u, i + 2), cK[i + 2], t2);
            t3 = fmaf(bcast(u, i + 3), cK[i + 3], t3);
        }
        const float t = (t0 + t1) + (t2 + t3);
        // v <- v / (v*t + eps)
        v = v * __builtin_amdgcn_rcpf(fmaf(v, t, kEps));
    }

    // O[i][lane] = u_i * K[i][lane] * v_lane   (fully coalesced)
#pragma unroll
    for (int i = 0; i < 64; ++i) {
        O[(i << 6) + lane] = bcast(u, i) * cK[i] * v;
    }
}

extern "C" void kernel_launch(void* const* d_in, const int* in_sizes, int n_in,
                              void* d_out, int out_size, void* d_ws, size_t ws_size,
                              hipStream_t stream) {
    const float* in = (const float*)d_in[0];
    float* out      = (float*)d_out;
    // 8192 matrices, 4 waves (4 matrices) per 256-thread block.
    sinkhorn64<<<2048, 256, 0, stream>>>(in, out);
}